// Round 6
// baseline (356.968 us; speedup 1.0000x reference)
//
#include <hip/hip_runtime.h>

// MultiHeadAttention: B=4, S=2048, D=1024, H=16, DH=64
// out = ((softmax(mask(QK^T/8)) V) merged) @ Wo^T
// bf16 MFMA, f32 accum. No-max softmax (Q pre-scaled by 0.125*log2e).
// This round: attn widened to 64 queries/wave (FOUR 16-q groups). K/V LDS
// reads + staging amortized 4x across independent MFMA chains -> MFMA pipe
// becomes the critical pipe (4.5 MFMA per ds_read_b128). Grid 512 blocks
// (64 bh x 8 q-chunks of 256) = exactly 2 blocks/CU, no tail.

#define BB 4
#define SS 2048
#define DD 1024
#define HH 16
#define DH 64

typedef __bf16 bf16x8 __attribute__((ext_vector_type(8)));
typedef float floatx4 __attribute__((ext_vector_type(4)));
typedef unsigned short ushortx8 __attribute__((ext_vector_type(8)));
typedef unsigned short ushortx4 __attribute__((ext_vector_type(4)));
typedef unsigned short ushort_t;

__device__ __forceinline__ unsigned short f2bf(float f) {
    unsigned u = __builtin_bit_cast(unsigned, f);
    u += 0x7FFFu + ((u >> 16) & 1u);   // RNE
    return (unsigned short)(u >> 16);
}

__device__ __forceinline__ bf16x8 ldb(const ushort_t* p) {
    return __builtin_bit_cast(bf16x8, *(const ushortx8*)p);
}

// async global->LDS, 16B per lane; lds dest must be wave-uniform base + lane*16
__device__ __forceinline__ void dma16(const ushort_t* g, ushort_t* l) {
    __builtin_amdgcn_global_load_lds(
        (const __attribute__((address_space(1))) unsigned int*)g,
        (__attribute__((address_space(3))) unsigned int*)l, 16, 0, 0);
}

__device__ __forceinline__ floatx4 mfma32(bf16x8 a, bf16x8 b, floatx4 c) {
    return __builtin_amdgcn_mfma_f32_16x16x32_bf16(a, b, c, 0, 0, 0);
}

__device__ __forceinline__ floatx4 fzero() {
    floatx4 z = {0.f, 0.f, 0.f, 0.f};
    return z;
}

// ---------------- f32 -> bf16 converts (merged dispatches) ----------------
__device__ __forceinline__ void cvt_body(const float* __restrict__ in,
                                         ushort_t* __restrict__ out) {
    int i = (blockIdx.x * blockDim.x + threadIdx.x) * 4;
    float4 f = *(const float4*)&in[i];
    ushortx4 o;
    o[0] = f2bf(f.x); o[1] = f2bf(f.y); o[2] = f2bf(f.z); o[3] = f2bf(f.w);
    *(ushortx4*)&out[i] = o;
}

__global__ void cvt3(const float* __restrict__ i0, const float* __restrict__ i1,
                     const float* __restrict__ i2, ushort_t* __restrict__ o0,
                     ushort_t* __restrict__ o1, ushort_t* __restrict__ o2) {
    const float* in = blockIdx.y == 0 ? i0 : blockIdx.y == 1 ? i1 : i2;
    ushort_t* out = blockIdx.y == 0 ? o0 : blockIdx.y == 1 ? o1 : o2;
    cvt_body(in, out);
}

__global__ void cvt4(const float* __restrict__ i0, const float* __restrict__ i1,
                     const float* __restrict__ i2, const float* __restrict__ i3,
                     ushort_t* __restrict__ o0, ushort_t* __restrict__ o1,
                     ushort_t* __restrict__ o2, ushort_t* __restrict__ o3) {
    const float* in = blockIdx.y == 0 ? i0 : blockIdx.y == 1 ? i1
                     : blockIdx.y == 2 ? i2 : i3;
    ushort_t* out = blockIdx.y == 0 ? o0 : blockIdx.y == 1 ? o1
                   : blockIdx.y == 2 ? o2 : o3;
    cvt_body(in, out);
}

// ---------------- GEMM core: acc[m][n] = sum_k A[m,k] * B[n,k] ----------------
// 128x128 tile, BK=32, double-buffered LDS: stage tile t+1 before computing
// tile t; one __syncthreads (vmcnt0+lgkm0 drain) per K-step.
__device__ __forceinline__ void gemm_core(
    const ushort_t* __restrict__ Ab, const ushort_t* __restrict__ Bb,
    floatx4 acc[4][4], ushort_t (*As)[128][32], ushort_t (*Bs)[128][32], int tid)
{
    const int wv = tid >> 6, lane = tid & 63;
    const int quad = lane >> 4, lid = lane & 15;
    const int wm = wv & 1, wn = wv >> 1;
    const int r0 = lane >> 2, c0 = (lane & 3) * 8;

#pragma unroll
    for (int i = 0; i < 4; ++i)
#pragma unroll
        for (int j = 0; j < 4; ++j) acc[i][j] = fzero();

    // prologue: stage k0=0 into buffer 0
#pragma unroll
    for (int s = 0; s < 2; ++s) {
        int seg = wv * 2 + s;
        dma16(&Ab[(size_t)(seg * 16 + r0) * DD + c0], &As[0][seg * 16][0]);
        dma16(&Bb[(size_t)(seg * 16 + r0) * DD + c0], &Bs[0][seg * 16][0]);
    }
    __syncthreads();

    int cur = 0;
    for (int k0 = 0; k0 < DD; k0 += 32) {
        int nxt = cur ^ 1;
        if (k0 + 32 < DD) {
#pragma unroll
            for (int s = 0; s < 2; ++s) {
                int seg = wv * 2 + s;
                dma16(&Ab[(size_t)(seg * 16 + r0) * DD + k0 + 32 + c0], &As[nxt][seg * 16][0]);
                dma16(&Bb[(size_t)(seg * 16 + r0) * DD + k0 + 32 + c0], &Bs[nxt][seg * 16][0]);
            }
        }
        bf16x8 af[4], bfr[4];
#pragma unroll
        for (int mt = 0; mt < 4; ++mt) af[mt] = ldb(&As[cur][wm * 64 + mt * 16 + lid][quad * 8]);
#pragma unroll
        for (int nt = 0; nt < 4; ++nt) bfr[nt] = ldb(&Bs[cur][wn * 64 + nt * 16 + lid][quad * 8]);
#pragma unroll
        for (int mt = 0; mt < 4; ++mt)
#pragma unroll
            for (int nt = 0; nt < 4; ++nt)
                acc[mt][nt] = mfma32(af[mt], bfr[nt], acc[mt][nt]);
        __syncthreads();   // drains this iter's prefetch (vmcnt0) + ds reads
        cur = nxt;
    }
}

// ---------------- fused QKV projection ----------------
// flat grid 1536, XCD swizzle: xcd f&7 owns 192 consecutive logical blocks =
// by-range of 8 (all 24 bx) -> A-slices fetched once per XCD. logical =
// by*24+bx; bx>>3 selects {query,key,value}. Q: (B,H,S,DH) pre-scaled by
// 0.125*log2e. K: (B,H,S,DH), masked rows ZEROED (so attn's P=exp2(0)=1 for
// masked keys; denominator corrected by n_masked). V: (B,H,DH,S) = V^T with
// mask folded in. Epilogue transpose buffer Ts ALIASES As (dead after the
// K-loop's final barrier) -> LDS 32 KB -> 5 blocks/CU.
__global__ __launch_bounds__(256) void gemm_qkv(
    const ushort_t* __restrict__ Qa, const ushort_t* __restrict__ Ka,
    const ushort_t* __restrict__ Va, const ushort_t* __restrict__ Wqkv,
    const int* __restrict__ maskg,
    ushort_t* __restrict__ Qp, ushort_t* __restrict__ Kp, ushort_t* __restrict__ Vtp)
{
    __shared__ ushort_t As[2][128][32];
    __shared__ ushort_t Bs[2][128][32];
    // per-wave epilogue transpose buffer, aliased onto As (16384 B >= 9216 B);
    // safe: last As read precedes the K-loop's final __syncthreads.
    ushort_t (*Ts)[16][72] = reinterpret_cast<ushort_t (*)[16][72]>(&As[0][0][0]);

    const int tid = threadIdx.x;
    const int f = blockIdx.x;
    const int logical = (f & 7) * 192 + (f >> 3);
    const int by = logical / 24;
    const int bxx = logical % 24;
    const int which = bxx >> 3;
    const int m0 = by * 128;
    const int n0 = bxx * 128;
    const ushort_t* Ab = (which == 0 ? Qa : which == 1 ? Ka : Va) + (size_t)m0 * DD;
    const ushort_t* Bb = Wqkv + (size_t)n0 * DD;

    floatx4 acc[4][4];
    gemm_core(Ab, Bb, acc, As, Bs, tid);

    const int wv = tid >> 6, lane = tid & 63;
    const int quad = lane >> 4, lid = lane & 15;
    const int wm = wv & 1, wn = wv >> 1;
    const int b = m0 >> 11;                 // batch uniform per block
    const int sbase = (m0 & 2047) + wm * 64;
    const int nl0 = n0 - which * 1024 + wn * 64;   // local n base of this wave
    const int sl = lane >> 2, cl = (lane & 3) * 16;
    const int* maskb = maskg + b * SS;

    if (which == 2) {
        // V^T: (B,H,DH,S), masked. Per nt: pack 4 s-consecutive vals -> b64 LDS,
        // read back dh-rows of 16 s-contiguous -> dwordx4 stores.
#pragma unroll
        for (int nt = 0; nt < 4; ++nt) {
#pragma unroll
            for (int mt = 0; mt < 4; ++mt) {
                int sp = sbase + mt * 16 + quad * 4;
                int4 mv = *(const int4*)&maskb[sp];
                ushortx4 o;
                o[0] = mv.x ? (ushort_t)0 : f2bf(acc[mt][nt][0]);
                o[1] = mv.y ? (ushort_t)0 : f2bf(acc[mt][nt][1]);
                o[2] = mv.z ? (ushort_t)0 : f2bf(acc[mt][nt][2]);
                o[3] = mv.w ? (ushort_t)0 : f2bf(acc[mt][nt][3]);
                *(ushortx4*)&Ts[wv][lid][mt * 16 + quad * 4] = o;
            }
            ushortx8 w0 = *(const ushortx8*)&Ts[wv][sl][cl];
            ushortx8 w1 = *(const ushortx8*)&Ts[wv][sl][cl + 8];
            int nl = nl0 + nt * 16 + sl;
            int h = nl >> 6, dh = nl & 63;
            size_t base = (((size_t)b * HH + h) * DH + dh) * SS + sbase + cl;
            *(ushortx8*)&Vtp[base] = w0;
            *(ushortx8*)&Vtp[base + 8] = w1;
        }
    } else {
        // Q/K: (B,H,S,DH). K rows for masked keys zeroed. Per mt: scatter 16
        // b16 into LDS s-major tile, read back s-rows -> dwordx4 stores.
        ushort_t* P = which ? Kp : Qp;
        const float scl = which ? 1.0f : 0.125f * 1.4426950408889634f;
        const int h = nl0 >> 6;
#pragma unroll
        for (int mt = 0; mt < 4; ++mt) {
            int mvr[4] = {0, 0, 0, 0};
            if (which) {
                int4 mv = *(const int4*)&maskb[sbase + mt * 16 + quad * 4];
                mvr[0] = mv.x; mvr[1] = mv.y; mvr[2] = mv.z; mvr[3] = mv.w;
            }
#pragma unroll
            for (int nt = 0; nt < 4; ++nt)
#pragma unroll
                for (int r = 0; r < 4; ++r)
                    Ts[wv][quad * 4 + r][nt * 16 + lid] =
                        mvr[r] ? (ushort_t)0 : f2bf(acc[mt][nt][r] * scl);
            ushortx8 w0 = *(const ushortx8*)&Ts[wv][sl][cl];
            ushortx8 w1 = *(const ushortx8*)&Ts[wv][sl][cl + 8];
            int s = sbase + mt * 16 + sl;
            size_t base = (((size_t)b * HH + h) * SS + s) * DH + (nl0 & 63) + cl;
            *(ushortx8*)&P[base] = w0;
            *(ushortx8*)&P[base + 8] = w1;
        }
    }
}

// ---------------- final projection: out = Cx @ Wo^T, f32 out ----------------
// flat grid 512, XCD swizzle: xcd owns by-range of 8 (all 8 bx).
__global__ __launch_bounds__(256) void gemm_o(
    const ushort_t* __restrict__ Cx, const ushort_t* __restrict__ Wo,
    float* __restrict__ Out)
{
    __shared__ ushort_t As[2][128][32];
    __shared__ ushort_t Bs[2][128][32];
    const int tid = threadIdx.x;
    const int f = blockIdx.x;
    const int logical = (f & 7) * 64 + (f >> 3);
    const int by = logical >> 3, bx = logical & 7;
    const int m0 = by * 128;
    const int n0 = bx * 128;

    floatx4 acc[4][4];
    gemm_core(Cx + (size_t)m0 * DD, Wo + (size_t)n0 * DD, acc, As, Bs, tid);

    const int wv = tid >> 6, lane = tid & 63;
    const int quad = lane >> 4, lid = lane & 15;
    const int wm = wv & 1, wn = wv >> 1;
#pragma unroll
    for (int mt = 0; mt < 4; ++mt)
#pragma unroll
        for (int nt = 0; nt < 4; ++nt)
#pragma unroll
            for (int r = 0; r < 4; ++r) {
                int m = m0 + wm * 64 + mt * 16 + quad * 4 + r;
                int n = n0 + wn * 64 + nt * 16 + lid;
                Out[(size_t)m * DD + n] = acc[mt][nt][r];
            }
}

// ---------------- flash attention (S^T scheme, K=32 PV, 64 q/wave) ----------
// flat grid 512, XCD swizzle: xcd=id&7 owns 8 bh (K/V L2-resident, 4 MB/XCD).
// Per wave: 64 queries = FOUR 16-q groups sharing all K/V LDS reads (4.5 MFMA
// per ds_read_b128; MFMA pipe critical). S^T = K·Q^T with key rows PERMUTED
// in LDS (p = 32kk+8quad+4h+r stored at row 32kk+16h+4quad+r) so the S^T
// output of an mt-pair is in-register in exact K=32 A-fragment layout -> PV
// and denominator run as full-rate mfma32. Mask: masked K rows are zero
// (S=0 -> P=1); masked V^T cols zero; denominator = mfma(P, ones) - n_masked.
// LDS 32 KB. Double-buffered staging via global_load_lds with 16B-XOR
// pre-swizzled source; conflict-free reads.
__global__ __launch_bounds__(256) void attn_kernel(
    const ushort_t* __restrict__ Qg, const ushort_t* __restrict__ Kg,
    const ushort_t* __restrict__ Vtg, const int* __restrict__ maskg,
    ushort_t* __restrict__ Ctx)
{
    __shared__ ushort_t Ks[2][64 * 64];    // [buf][perm key row][dh ^ swz]  16 KB
    __shared__ ushort_t Vts[2][64 * 64];   // [buf][dh][key ^ swz] (pre-masked) 16 KB

    const int flat = blockIdx.x;
    const int xcd = flat & 7;
    const int slot = flat >> 3;            // 0..63
    const int bh = xcd * 8 + (slot >> 3);
    const int qc = slot & 7;               // 8 q-chunks of 256
    const int b = bh >> 4, h = bh & 15;
    const int tid = threadIdx.x;
    const int wv = tid >> 6, lane = tid & 63;
    const int quad = lane >> 4, lid = lane & 15;

    const ushort_t* Qb = Qg + (size_t)bh * SS * DH;
    const ushort_t* Kb = Kg + (size_t)bh * SS * DH;
    const ushort_t* Vtb = Vtg + (size_t)bh * DH * SS;
    const int* maskb = maskg + b * SS;

    // n_masked for this batch: 32 ints/lane + wave shuffle-reduce (one-time)
    int nm = 0;
    {
        const int4* m4 = (const int4*)maskb;
#pragma unroll
        for (int i = 0; i < 8; ++i) {
            int4 m = m4[lane + i * 64];
            nm += m.x + m.y + m.z + m.w;
        }
#pragma unroll
        for (int off = 32; off; off >>= 1) nm += __shfl_xor(nm, off);
    }
    const float nmf = (float)nm;

    const int qbase = qc * 256 + wv * 64;

    bf16x8 qf[4][2];   // [group][dh half]; B-operand: n=lid -> query, k=dh
#pragma unroll
    for (int g = 0; g < 4; ++g) {
        const int row = qbase + g * 16 + lid;
        qf[g][0] = ldb(&Qb[(size_t)row * DH + quad * 8]);
        qf[g][1] = ldb(&Qb[(size_t)row * DH + 32 + quad * 8]);
    }

    // constant ones B-operand for the denominator
    ushortx8 ov;
#pragma unroll
    for (int i = 0; i < 8; ++i) ov[i] = (ushort_t)0x3F80;
    const bf16x8 ones = __builtin_bit_cast(bf16x8, ov);

    // per-lane staging source offsets (elements), computed once.
    // lane covers LDS 16B chunk idx = wv*128 + s*64 + lane: ldsrow=idx>>3,
    // chunk c16=idx&7. K source row = perm(ldsrow); col chunk = c16 ^ (row&7).
    int offK[2], offV[2];
#pragma unroll
    for (int s = 0; s < 2; ++s) {
        int idx = wv * 128 + s * 64 + lane;
        int row = idx >> 3;
        int c16 = idx & 7;
        // perm: row bits [kk h quad r] -> p bits [kk quad h r]
        int p = (row & 35) | ((row & 12) << 1) | ((row & 16) >> 2);
        int colu = (c16 ^ (row & 7)) << 3;
        offK[s] = p * DH + colu;
        offV[s] = row * SS + colu;
    }

    floatx4 Oacc[4][4];   // [group][nt]
    floatx4 Osum[4];
#pragma unroll
    for (int g = 0; g < 4; ++g) {
        Osum[g] = fzero();
#pragma unroll
        for (int i = 0; i < 4; ++i) Oacc[g][i] = fzero();
    }

    const int swz = (lid & 7) << 3;

    // prologue: stage kc=0 into buffer 0
    dma16(Kb + offK[0], &Ks[0][(wv * 2 + 0) * 512]);
    dma16(Kb + offK[1], &Ks[0][(wv * 2 + 1) * 512]);
    dma16(Vtb + offV[0], &Vts[0][(wv * 2 + 0) * 512]);
    dma16(Vtb + offV[1], &Vts[0][(wv * 2 + 1) * 512]);
    __syncthreads();

    const ushort_t* Kc = Kb + 64 * DH;   // next-tile pointers
    const ushort_t* Vc = Vtb + 64;
    int cur = 0;

    for (int kc = 0; kc < SS / 64; ++kc) {
        int nxt = cur ^ 1;
        if (kc + 1 < SS / 64) {
            dma16(Kc + offK[0], &Ks[nxt][(wv * 2 + 0) * 512]);
            dma16(Kc + offK[1], &Ks[nxt][(wv * 2 + 1) * 512]);
            dma16(Vc + offV[0], &Vts[nxt][(wv * 2 + 0) * 512]);
            dma16(Vc + offV[1], &Vts[nxt][(wv * 2 + 1) * 512]);
            Kc += 64 * DH;
            Vc += 64;
        }

        // per 32-key block kk: S^T for all 4 q-groups (K reads shared), exp2,
        // then PV + denominator (V reads shared across groups).
#pragma unroll
        for (int kk = 0; kk < 2; ++kk) {
            floatx4 st[4][2];   // [group][m2]
#pragma unroll
            for (int m2 = 0; m2 < 2; ++m2) {
                const int mt = kk * 2 + m2;
                const int rb = (mt * 16 + lid) * 64;
                bf16x8 kf0 = ldb(&Ks[cur][rb + ((quad * 8) ^ swz)]);
                bf16x8 kf1 = ldb(&Ks[cur][rb + ((32 + quad * 8) ^ swz)]);
#pragma unroll
                for (int g = 0; g < 4; ++g)
                    st[g][m2] = mfma32(kf1, qf[g][1], mfma32(kf0, qf[g][0], fzero()));
            }
            bf16x8 p[4];
#pragma unroll
            for (int g = 0; g < 4; ++g) {
#pragma unroll
                for (int r = 0; r < 4; ++r) {
                    p[g][r]     = (__bf16)__builtin_amdgcn_exp2f(st[g][0][r]);
                    p[g][r + 4] = (__bf16)__builtin_amdgcn_exp2f(st[g][1][r]);
                }
                Osum[g] = mfma32(p[g], ones, Osum[g]);
            }
#pragma unroll
            for (int nt = 0; nt < 4; ++nt) {
                bf16x8 vb = ldb(&Vts[cur][(nt * 16 + lid) * 64 + ((kk * 32 + quad * 8) ^ swz)]);
#pragma unroll
                for (int g = 0; g < 4; ++g)
                    Oacc[g][nt] = mfma32(p[g], vb, Oacc[g][nt]);
            }
        }
        __syncthreads();   // drains prefetch (vmcnt0) + this tile's ds reads
        cur = nxt;
    }

    // Osum[g][r] = row sum for q = qbase+g*16+quad*4+r, includes +1 per masked
    // key (P=1 there) -> subtract nmf.
#pragma unroll
    for (int g = 0; g < 4; ++g) {
        float inv[4];
#pragma unroll
        for (int r = 0; r < 4; ++r) inv[r] = 1.0f / (Osum[g][r] - nmf);
#pragma unroll
        for (int nt = 0; nt < 4; ++nt) {
#pragma unroll
            for (int r = 0; r < 4; ++r) {
                int s = qbase + g * 16 + quad * 4 + r;
                int dh = nt * 16 + lid;
                Ctx[(((size_t)b * SS + s) * HH + h) * DH + dh] = f2bf(Oacc[g][nt][r] * inv[r]);
            }
        }
    }
}

// ---------------- launch ----------------
extern "C" void kernel_launch(void* const* d_in, const int* in_sizes, int n_in,
                              void* d_out, int out_size, void* d_ws, size_t ws_size,
                              hipStream_t stream) {
    const float* q  = (const float*)d_in[0];
    const float* k  = (const float*)d_in[1];
    const float* v  = (const float*)d_in[2];
    const int*   mask = (const int*)d_in[3];
    const float* Wq = (const float*)d_in[4];
    const float* Wk = (const float*)d_in[5];
    const float* Wv = (const float*)d_in[6];
    const float* Wo = (const float*)d_in[7];
    float* out = (float*)d_out;

    char* ws = (char*)d_ws;
    const size_t MB = 1024 * 1024;
    ushort_t* Qin  = (ushort_t*)(ws + 0 * MB);    // 16 MB each
    ushort_t* Kin  = (ushort_t*)(ws + 16 * MB);
    ushort_t* Vin  = (ushort_t*)(ws + 32 * MB);
    ushort_t* Qp   = (ushort_t*)(ws + 48 * MB);
    ushort_t* Kp   = (ushort_t*)(ws + 64 * MB);
    ushort_t* Vtp  = (ushort_t*)(ws + 80 * MB);
    ushort_t* Wqkv = (ushort_t*)(ws + 96 * MB);   // 6 MB
    ushort_t* Wob  = (ushort_t*)(ws + 102 * MB);  // 2 MB
    ushort_t* Cx   = Qin;                         // Qin dead after gemm_qkv

    const int INEL = BB * SS * DD;   // 8.4M
    const int WN = DD * DD;          // 1M
    cvt3<<<dim3(INEL / 1024, 3), 256, 0, stream>>>(q, k, v, Qin, Kin, Vin);
    cvt4<<<dim3(WN / 1024, 4), 256, 0, stream>>>(Wq, Wk, Wv, Wo,
                                                 Wqkv, Wqkv + WN, Wqkv + 2 * WN, Wob);

    gemm_qkv<<<dim3(1536), 256, 0, stream>>>(Qin, Kin, Vin, Wqkv, mask, Qp, Kp, Vtp);
    attn_kernel<<<dim3(512), 256, 0, stream>>>(Qp, Kp, Vtp, mask, Cx);
    gemm_o<<<dim3(512), 256, 0, stream>>>(Cx, Wob, out);
}

// Round 7
// 325.239 us; speedup vs baseline: 1.0976x; 1.0976x over previous
//
#include <hip/hip_runtime.h>

// MultiHeadAttention: B=4, S=2048, D=1024, H=16, DH=64
// out = ((softmax(mask(QK^T/8)) V) merged) @ Wo^T
// bf16 MFMA, f32 accum. No-max softmax (Q pre-scaled by 0.125*log2e).
// This round: REVERT attn to the proven 32 q/wave structure (round-5, 92 us;
// the 64 q/wave variant collapsed occupancy 32->11% and regressed to 117).
// Added: s_setprio(1) around attn MFMA clusters (T5, attn-positive only);
// all f32->bf16 converts merged into ONE dispatch (4 total dispatches).

#define BB 4
#define SS 2048
#define DD 1024
#define HH 16
#define DH 64

typedef __bf16 bf16x8 __attribute__((ext_vector_type(8)));
typedef float floatx4 __attribute__((ext_vector_type(4)));
typedef unsigned short ushortx8 __attribute__((ext_vector_type(8)));
typedef unsigned short ushortx4 __attribute__((ext_vector_type(4)));
typedef unsigned short ushort_t;

__device__ __forceinline__ unsigned short f2bf(float f) {
    unsigned u = __builtin_bit_cast(unsigned, f);
    u += 0x7FFFu + ((u >> 16) & 1u);   // RNE
    return (unsigned short)(u >> 16);
}

__device__ __forceinline__ bf16x8 ldb(const ushort_t* p) {
    return __builtin_bit_cast(bf16x8, *(const ushortx8*)p);
}

// async global->LDS, 16B per lane; lds dest must be wave-uniform base + lane*16
__device__ __forceinline__ void dma16(const ushort_t* g, ushort_t* l) {
    __builtin_amdgcn_global_load_lds(
        (const __attribute__((address_space(1))) unsigned int*)g,
        (__attribute__((address_space(3))) unsigned int*)l, 16, 0, 0);
}

__device__ __forceinline__ floatx4 mfma32(bf16x8 a, bf16x8 b, floatx4 c) {
    return __builtin_amdgcn_mfma_f32_16x16x32_bf16(a, b, c, 0, 0, 0);
}

__device__ __forceinline__ floatx4 fzero() {
    floatx4 z = {0.f, 0.f, 0.f, 0.f};
    return z;
}

// ---------------- f32 -> bf16 convert (single dispatch for all 7 arrays) ----
__global__ void cvt_all(const float* __restrict__ q, const float* __restrict__ k,
                        const float* __restrict__ v, const float* __restrict__ wq,
                        const float* __restrict__ wk, const float* __restrict__ wv,
                        const float* __restrict__ wo,
                        ushort_t* __restrict__ oq, ushort_t* __restrict__ ok,
                        ushort_t* __restrict__ ov, ushort_t* __restrict__ owqkv,
                        ushort_t* __restrict__ owo) {
    const int bid = blockIdx.x;   // 28672 blocks, 1024 els each
    const float* in; ushort_t* out; int rel;
    if (bid < 8192)        { in = q;  out = oq;            rel = bid; }
    else if (bid < 16384)  { in = k;  out = ok;            rel = bid - 8192; }
    else if (bid < 24576)  { in = v;  out = ov;            rel = bid - 16384; }
    else if (bid < 25600)  { in = wq; out = owqkv;         rel = bid - 24576; }
    else if (bid < 26624)  { in = wk; out = owqkv + 1048576; rel = bid - 25600; }
    else if (bid < 27648)  { in = wv; out = owqkv + 2097152; rel = bid - 26624; }
    else                   { in = wo; out = owo;           rel = bid - 27648; }
    int i = rel * 1024 + threadIdx.x * 4;
    float4 f = *(const float4*)&in[i];
    ushortx4 o;
    o[0] = f2bf(f.x); o[1] = f2bf(f.y); o[2] = f2bf(f.z); o[3] = f2bf(f.w);
    *(ushortx4*)&out[i] = o;
}

// ---------------- GEMM core: acc[m][n] = sum_k A[m,k] * B[n,k] ----------------
// 128x128 tile, BK=32, double-buffered LDS: stage tile t+1 before computing
// tile t; one __syncthreads (vmcnt0+lgkm0 drain) per K-step.
__device__ __forceinline__ void gemm_core(
    const ushort_t* __restrict__ Ab, const ushort_t* __restrict__ Bb,
    floatx4 acc[4][4], ushort_t (*As)[128][32], ushort_t (*Bs)[128][32], int tid)
{
    const int wv = tid >> 6, lane = tid & 63;
    const int quad = lane >> 4, lid = lane & 15;
    const int wm = wv & 1, wn = wv >> 1;
    const int r0 = lane >> 2, c0 = (lane & 3) * 8;

#pragma unroll
    for (int i = 0; i < 4; ++i)
#pragma unroll
        for (int j = 0; j < 4; ++j) acc[i][j] = fzero();

    // prologue: stage k0=0 into buffer 0
#pragma unroll
    for (int s = 0; s < 2; ++s) {
        int seg = wv * 2 + s;
        dma16(&Ab[(size_t)(seg * 16 + r0) * DD + c0], &As[0][seg * 16][0]);
        dma16(&Bb[(size_t)(seg * 16 + r0) * DD + c0], &Bs[0][seg * 16][0]);
    }
    __syncthreads();

    int cur = 0;
    for (int k0 = 0; k0 < DD; k0 += 32) {
        int nxt = cur ^ 1;
        if (k0 + 32 < DD) {
#pragma unroll
            for (int s = 0; s < 2; ++s) {
                int seg = wv * 2 + s;
                dma16(&Ab[(size_t)(seg * 16 + r0) * DD + k0 + 32 + c0], &As[nxt][seg * 16][0]);
                dma16(&Bb[(size_t)(seg * 16 + r0) * DD + k0 + 32 + c0], &Bs[nxt][seg * 16][0]);
            }
        }
        bf16x8 af[4], bfr[4];
#pragma unroll
        for (int mt = 0; mt < 4; ++mt) af[mt] = ldb(&As[cur][wm * 64 + mt * 16 + lid][quad * 8]);
#pragma unroll
        for (int nt = 0; nt < 4; ++nt) bfr[nt] = ldb(&Bs[cur][wn * 64 + nt * 16 + lid][quad * 8]);
#pragma unroll
        for (int mt = 0; mt < 4; ++mt)
#pragma unroll
            for (int nt = 0; nt < 4; ++nt)
                acc[mt][nt] = mfma32(af[mt], bfr[nt], acc[mt][nt]);
        __syncthreads();   // drains this iter's prefetch (vmcnt0) + ds reads
        cur = nxt;
    }
}

// ---------------- fused QKV projection ----------------
// flat grid 1536, XCD swizzle: xcd f&7 owns 192 consecutive logical blocks =
// by-range of 8 (all 24 bx) -> A-slices fetched once per XCD. logical =
// by*24+bx; bx>>3 selects {query,key,value}. Q: (B,H,S,DH) pre-scaled by
// 0.125*log2e. K: (B,H,S,DH), masked rows ZEROED (so attn's P=exp2(0)=1 for
// masked keys; denominator corrected by n_masked). V: (B,H,DH,S) = V^T with
// mask folded in. Epilogue transpose buffer Ts ALIASES As (dead after the
// K-loop's final barrier) -> LDS 32 KB -> 5 blocks/CU.
__global__ __launch_bounds__(256) void gemm_qkv(
    const ushort_t* __restrict__ Qa, const ushort_t* __restrict__ Ka,
    const ushort_t* __restrict__ Va, const ushort_t* __restrict__ Wqkv,
    const int* __restrict__ maskg,
    ushort_t* __restrict__ Qp, ushort_t* __restrict__ Kp, ushort_t* __restrict__ Vtp)
{
    __shared__ ushort_t As[2][128][32];
    __shared__ ushort_t Bs[2][128][32];
    // per-wave epilogue transpose buffer, aliased onto As (16384 B >= 9216 B);
    // safe: last As read precedes the K-loop's final __syncthreads.
    ushort_t (*Ts)[16][72] = reinterpret_cast<ushort_t (*)[16][72]>(&As[0][0][0]);

    const int tid = threadIdx.x;
    const int f = blockIdx.x;
    const int logical = (f & 7) * 192 + (f >> 3);
    const int by = logical / 24;
    const int bxx = logical % 24;
    const int which = bxx >> 3;
    const int m0 = by * 128;
    const int n0 = bxx * 128;
    const ushort_t* Ab = (which == 0 ? Qa : which == 1 ? Ka : Va) + (size_t)m0 * DD;
    const ushort_t* Bb = Wqkv + (size_t)n0 * DD;

    floatx4 acc[4][4];
    gemm_core(Ab, Bb, acc, As, Bs, tid);

    const int wv = tid >> 6, lane = tid & 63;
    const int quad = lane >> 4, lid = lane & 15;
    const int wm = wv & 1, wn = wv >> 1;
    const int b = m0 >> 11;                 // batch uniform per block
    const int sbase = (m0 & 2047) + wm * 64;
    const int nl0 = n0 - which * 1024 + wn * 64;   // local n base of this wave
    const int sl = lane >> 2, cl = (lane & 3) * 16;
    const int* maskb = maskg + b * SS;

    if (which == 2) {
        // V^T: (B,H,DH,S), masked. Per nt: pack 4 s-consecutive vals -> b64 LDS,
        // read back dh-rows of 16 s-contiguous -> dwordx4 stores.
#pragma unroll
        for (int nt = 0; nt < 4; ++nt) {
#pragma unroll
            for (int mt = 0; mt < 4; ++mt) {
                int sp = sbase + mt * 16 + quad * 4;
                int4 mv = *(const int4*)&maskb[sp];
                ushortx4 o;
                o[0] = mv.x ? (ushort_t)0 : f2bf(acc[mt][nt][0]);
                o[1] = mv.y ? (ushort_t)0 : f2bf(acc[mt][nt][1]);
                o[2] = mv.z ? (ushort_t)0 : f2bf(acc[mt][nt][2]);
                o[3] = mv.w ? (ushort_t)0 : f2bf(acc[mt][nt][3]);
                *(ushortx4*)&Ts[wv][lid][mt * 16 + quad * 4] = o;
            }
            ushortx8 w0 = *(const ushortx8*)&Ts[wv][sl][cl];
            ushortx8 w1 = *(const ushortx8*)&Ts[wv][sl][cl + 8];
            int nl = nl0 + nt * 16 + sl;
            int h = nl >> 6, dh = nl & 63;
            size_t base = (((size_t)b * HH + h) * DH + dh) * SS + sbase + cl;
            *(ushortx8*)&Vtp[base] = w0;
            *(ushortx8*)&Vtp[base + 8] = w1;
        }
    } else {
        // Q/K: (B,H,S,DH). K rows for masked keys zeroed. Per mt: scatter 16
        // b16 into LDS s-major tile, read back s-rows -> dwordx4 stores.
        ushort_t* P = which ? Kp : Qp;
        const float scl = which ? 1.0f : 0.125f * 1.4426950408889634f;
        const int h = nl0 >> 6;
#pragma unroll
        for (int mt = 0; mt < 4; ++mt) {
            int mvr[4] = {0, 0, 0, 0};
            if (which) {
                int4 mv = *(const int4*)&maskb[sbase + mt * 16 + quad * 4];
                mvr[0] = mv.x; mvr[1] = mv.y; mvr[2] = mv.z; mvr[3] = mv.w;
            }
#pragma unroll
            for (int nt = 0; nt < 4; ++nt)
#pragma unroll
                for (int r = 0; r < 4; ++r)
                    Ts[wv][quad * 4 + r][nt * 16 + lid] =
                        mvr[r] ? (ushort_t)0 : f2bf(acc[mt][nt][r] * scl);
            ushortx8 w0 = *(const ushortx8*)&Ts[wv][sl][cl];
            ushortx8 w1 = *(const ushortx8*)&Ts[wv][sl][cl + 8];
            int s = sbase + mt * 16 + sl;
            size_t base = (((size_t)b * HH + h) * SS + s) * DH + (nl0 & 63) + cl;
            *(ushortx8*)&P[base] = w0;
            *(ushortx8*)&P[base + 8] = w1;
        }
    }
}

// ---------------- final projection: out = Cx @ Wo^T, f32 out ----------------
// flat grid 512, XCD swizzle: xcd owns by-range of 8 (all 8 bx).
__global__ __launch_bounds__(256) void gemm_o(
    const ushort_t* __restrict__ Cx, const ushort_t* __restrict__ Wo,
    float* __restrict__ Out)
{
    __shared__ ushort_t As[2][128][32];
    __shared__ ushort_t Bs[2][128][32];
    const int tid = threadIdx.x;
    const int f = blockIdx.x;
    const int logical = (f & 7) * 64 + (f >> 3);
    const int by = logical >> 3, bx = logical & 7;
    const int m0 = by * 128;
    const int n0 = bx * 128;

    floatx4 acc[4][4];
    gemm_core(Cx + (size_t)m0 * DD, Wo + (size_t)n0 * DD, acc, As, Bs, tid);

    const int wv = tid >> 6, lane = tid & 63;
    const int quad = lane >> 4, lid = lane & 15;
    const int wm = wv & 1, wn = wv >> 1;
#pragma unroll
    for (int mt = 0; mt < 4; ++mt)
#pragma unroll
        for (int nt = 0; nt < 4; ++nt)
#pragma unroll
            for (int r = 0; r < 4; ++r) {
                int m = m0 + wm * 64 + mt * 16 + quad * 4 + r;
                int n = n0 + wn * 64 + nt * 16 + lid;
                Out[(size_t)m * DD + n] = acc[mt][nt][r];
            }
}

// ---------------- flash attention (S^T scheme, K=32 PV, 32 q/wave) ----------
// flat grid 1024, XCD swizzle: xcd=id&7 owns 8 bh (K/V L2-resident).
// Per wave: 32 queries = two 16-q groups sharing all K/V LDS reads.
// S^T = K·Q^T with key rows PERMUTED in LDS (p = 32kk+8quad+4h+r stored at
// row 32kk+16h+4quad+r) so the S^T output of an mt-pair is in-register in
// exact K=32 A-fragment layout -> PV and denominator run as full-rate mfma32.
// Mask handling: masked K rows are zero (S=0 -> P=1); masked V^T cols zero;
// denominator = mfma(P, ones) - n_masked (per-batch scalar, wave-reduced).
// LDS exactly 32 KB. setprio(1) around MFMA clusters (T5). Double-buffered
// staging via global_load_lds with 16B-XOR pre-swizzled source.
__global__ __launch_bounds__(256) void attn_kernel(
    const ushort_t* __restrict__ Qg, const ushort_t* __restrict__ Kg,
    const ushort_t* __restrict__ Vtg, const int* __restrict__ maskg,
    ushort_t* __restrict__ Ctx)
{
    __shared__ ushort_t Ks[2][64 * 64];    // [buf][perm key row][dh ^ swz]  16 KB
    __shared__ ushort_t Vts[2][64 * 64];   // [buf][dh][key ^ swz] (pre-masked) 16 KB

    const int flat = blockIdx.x;
    const int xcd = flat & 7;
    const int slot = flat >> 3;            // 0..127
    const int bh = xcd * 8 + (slot >> 4);
    const int qc = slot & 15;
    const int b = bh >> 4, h = bh & 15;
    const int tid = threadIdx.x;
    const int wv = tid >> 6, lane = tid & 63;
    const int quad = lane >> 4, lid = lane & 15;

    const ushort_t* Qb = Qg + (size_t)bh * SS * DH;
    const ushort_t* Kb = Kg + (size_t)bh * SS * DH;
    const ushort_t* Vtb = Vtg + (size_t)bh * DH * SS;
    const int* maskb = maskg + b * SS;

    // n_masked for this batch: 32 ints/lane + wave shuffle-reduce (one-time)
    int nm = 0;
    {
        const int4* m4 = (const int4*)maskb;
#pragma unroll
        for (int i = 0; i < 8; ++i) {
            int4 m = m4[lane + i * 64];
            nm += m.x + m.y + m.z + m.w;
        }
#pragma unroll
        for (int off = 32; off; off >>= 1) nm += __shfl_xor(nm, off);
    }
    const float nmf = (float)nm;

    const int qbase = qc * 128 + wv * 32;

    bf16x8 qf[2][2];   // [group][dh half]; B-operand: n=lid -> query, k=dh
#pragma unroll
    for (int g = 0; g < 2; ++g) {
        const int row = qbase + g * 16 + lid;
        qf[g][0] = ldb(&Qb[(size_t)row * DH + quad * 8]);
        qf[g][1] = ldb(&Qb[(size_t)row * DH + 32 + quad * 8]);
    }

    // constant ones B-operand for the denominator
    ushortx8 ov;
#pragma unroll
    for (int i = 0; i < 8; ++i) ov[i] = (ushort_t)0x3F80;
    const bf16x8 ones = __builtin_bit_cast(bf16x8, ov);

    // per-lane staging source offsets (elements), computed once.
    // lane covers LDS 16B chunk idx = wv*128 + s*64 + lane: ldsrow=idx>>3,
    // chunk c16=idx&7. K source row = perm(ldsrow); col chunk = c16 ^ (row&7).
    int offK[2], offV[2];
#pragma unroll
    for (int s = 0; s < 2; ++s) {
        int idx = wv * 128 + s * 64 + lane;
        int row = idx >> 3;
        int c16 = idx & 7;
        // perm: row bits [kk h quad r] -> p bits [kk quad h r]
        int p = (row & 35) | ((row & 12) << 1) | ((row & 16) >> 2);
        int colu = (c16 ^ (row & 7)) << 3;
        offK[s] = p * DH + colu;
        offV[s] = row * SS + colu;
    }

    floatx4 Oacc[2][4];
    floatx4 Osum[2];
#pragma unroll
    for (int g = 0; g < 2; ++g) {
        Osum[g] = fzero();
#pragma unroll
        for (int i = 0; i < 4; ++i) Oacc[g][i] = fzero();
    }

    const int swz = (lid & 7) << 3;

    // prologue: stage kc=0 into buffer 0
    dma16(Kb + offK[0], &Ks[0][(wv * 2 + 0) * 512]);
    dma16(Kb + offK[1], &Ks[0][(wv * 2 + 1) * 512]);
    dma16(Vtb + offV[0], &Vts[0][(wv * 2 + 0) * 512]);
    dma16(Vtb + offV[1], &Vts[0][(wv * 2 + 1) * 512]);
    __syncthreads();

    const ushort_t* Kc = Kb + 64 * DH;   // next-tile pointers
    const ushort_t* Vc = Vtb + 64;
    int cur = 0;

    for (int kc = 0; kc < SS / 64; ++kc) {
        int nxt = cur ^ 1;
        if (kc + 1 < SS / 64) {
            dma16(Kc + offK[0], &Ks[nxt][(wv * 2 + 0) * 512]);
            dma16(Kc + offK[1], &Ks[nxt][(wv * 2 + 1) * 512]);
            dma16(Vc + offV[0], &Vts[nxt][(wv * 2 + 0) * 512]);
            dma16(Vc + offV[1], &Vts[nxt][(wv * 2 + 1) * 512]);
            Kc += 64 * DH;
            Vc += 64;
        }

        // per 32-key block kk: S^T for both q-groups (K reads shared), exp2,
        // then PV + denominator (V reads shared across groups).
#pragma unroll
        for (int kk = 0; kk < 2; ++kk) {
            floatx4 sA[2], sB[2];
            __builtin_amdgcn_s_setprio(1);
#pragma unroll
            for (int m2 = 0; m2 < 2; ++m2) {
                const int mt = kk * 2 + m2;
                const int rb = (mt * 16 + lid) * 64;
                bf16x8 kf0 = ldb(&Ks[cur][rb + ((quad * 8) ^ swz)]);
                bf16x8 kf1 = ldb(&Ks[cur][rb + ((32 + quad * 8) ^ swz)]);
                sA[m2] = mfma32(kf1, qf[0][1], mfma32(kf0, qf[0][0], fzero()));
                sB[m2] = mfma32(kf1, qf[1][1], mfma32(kf0, qf[1][0], fzero()));
            }
            __builtin_amdgcn_s_setprio(0);
            bf16x8 pa, pb;
#pragma unroll
            for (int r = 0; r < 4; ++r) {
                pa[r]     = (__bf16)__builtin_amdgcn_exp2f(sA[0][r]);
                pa[r + 4] = (__bf16)__builtin_amdgcn_exp2f(sA[1][r]);
                pb[r]     = (__bf16)__builtin_amdgcn_exp2f(sB[0][r]);
                pb[r + 4] = (__bf16)__builtin_amdgcn_exp2f(sB[1][r]);
            }
            __builtin_amdgcn_s_setprio(1);
            Osum[0] = mfma32(pa, ones, Osum[0]);
            Osum[1] = mfma32(pb, ones, Osum[1]);
#pragma unroll
            for (int nt = 0; nt < 4; ++nt) {
                bf16x8 vb = ldb(&Vts[cur][(nt * 16 + lid) * 64 + ((kk * 32 + quad * 8) ^ swz)]);
                Oacc[0][nt] = mfma32(pa, vb, Oacc[0][nt]);
                Oacc[1][nt] = mfma32(pb, vb, Oacc[1][nt]);
            }
            __builtin_amdgcn_s_setprio(0);
        }
        __syncthreads();   // drains prefetch (vmcnt0) + this tile's ds reads
        cur = nxt;
    }

    // Osum[g][r] = row sum for q = qbase+g*16+quad*4+r, includes +1 per masked
    // key (P=1 there) -> subtract nmf.
#pragma unroll
    for (int g = 0; g < 2; ++g) {
        float inv[4];
#pragma unroll
        for (int r = 0; r < 4; ++r) inv[r] = 1.0f / (Osum[g][r] - nmf);
#pragma unroll
        for (int nt = 0; nt < 4; ++nt) {
#pragma unroll
            for (int r = 0; r < 4; ++r) {
                int s = qbase + g * 16 + quad * 4 + r;
                int dh = nt * 16 + lid;
                Ctx[(((size_t)b * SS + s) * HH + h) * DH + dh] = f2bf(Oacc[g][nt][r] * inv[r]);
            }
        }
    }
}

// ---------------- launch ----------------
extern "C" void kernel_launch(void* const* d_in, const int* in_sizes, int n_in,
                              void* d_out, int out_size, void* d_ws, size_t ws_size,
                              hipStream_t stream) {
    const float* q  = (const float*)d_in[0];
    const float* k  = (const float*)d_in[1];
    const float* v  = (const float*)d_in[2];
    const int*   mask = (const int*)d_in[3];
    const float* Wq = (const float*)d_in[4];
    const float* Wk = (const float*)d_in[5];
    const float* Wv = (const float*)d_in[6];
    const float* Wo = (const float*)d_in[7];
    float* out = (float*)d_out;

    char* ws = (char*)d_ws;
    const size_t MB = 1024 * 1024;
    ushort_t* Qin  = (ushort_t*)(ws + 0 * MB);    // 16 MB each
    ushort_t* Kin  = (ushort_t*)(ws + 16 * MB);
    ushort_t* Vin  = (ushort_t*)(ws + 32 * MB);
    ushort_t* Qp   = (ushort_t*)(ws + 48 * MB);
    ushort_t* Kp   = (ushort_t*)(ws + 64 * MB);
    ushort_t* Vtp  = (ushort_t*)(ws + 80 * MB);
    ushort_t* Wqkv = (ushort_t*)(ws + 96 * MB);   // 6 MB
    ushort_t* Wob  = (ushort_t*)(ws + 102 * MB);  // 2 MB
    ushort_t* Cx   = Qin;                         // Qin dead after gemm_qkv

    cvt_all<<<dim3(28672), 256, 0, stream>>>(q, k, v, Wq, Wk, Wv, Wo,
                                             Qin, Kin, Vin, Wqkv, Wob);

    gemm_qkv<<<dim3(1536), 256, 0, stream>>>(Qin, Kin, Vin, Wqkv, mask, Qp, Kp, Vtp);
    attn_kernel<<<dim3(1024), 256, 0, stream>>>(Qp, Kp, Vtp, mask, Cx);
    gemm_o<<<dim3(512), 256, 0, stream>>>(Cx, Wob, out);
}